// Round 8
// baseline (1279.719 us; speedup 1.0000x reference)
//
#include <hip/hip_runtime.h>
#include <stdint.h>

// Problem constants (B=4, S=4096, D=2048, H=16, G=4, hd=128)
#define M_DIM 16384   // B*S tokens
#define D_DIM 2048
#define HEADS 16
#define HDIM 128

typedef __attribute__((ext_vector_type(8))) short bf16x8;
typedef __attribute__((ext_vector_type(4))) float f32x4;

__device__ __forceinline__ unsigned short f2bf(float f) {
  union { float f; uint32_t u; } c; c.f = f;
  uint32_t u = c.u;
  u += 0x7FFFu + ((u >> 16) & 1u);   // round-to-nearest-even
  return (unsigned short)(u >> 16);
}
__device__ __forceinline__ float bf2f(unsigned short h) {
  union { float f; uint32_t u; } c; c.u = ((uint32_t)h) << 16;
  return c.f;
}

__device__ __forceinline__ void gload_lds16(const unsigned short* g, unsigned short* l) {
  __builtin_amdgcn_global_load_lds(
      (const __attribute__((address_space(1))) void*)g,
      (__attribute__((address_space(3))) void*)l,
      16, 0, 0);
}

// ---------------- x (fp32) -> bf16 ----------------
__global__ __launch_bounds__(256) void cvt_x_kernel(const float4* __restrict__ in,
                                                    unsigned short* __restrict__ out,
                                                    int n4) {
  int i = blockIdx.x * blockDim.x + threadIdx.x;
  int stride = gridDim.x * blockDim.x;
  for (; i < n4; i += stride) {
    float4 v = in[i];
    ushort4 o;
    o.x = f2bf(v.x); o.y = f2bf(v.y); o.z = f2bf(v.z); o.w = f2bf(v.w);
    ((ushort4*)out)[i] = o;
  }
}

// ------- W (fp32, [K][N]) -> W^T (bf16, [N][K]), all 4 weights in one grid ----
__global__ __launch_bounds__(256) void cvt_wt_kernel(const float* __restrict__ W0,
                                                     const float* __restrict__ W1,
                                                     const float* __restrict__ W2,
                                                     const float* __restrict__ W3,
                                                     unsigned short* __restrict__ Wt) {
  __shared__ float tile[32][33];
  const int z = blockIdx.z;
  const float* W = z == 0 ? W0 : (z == 1 ? W1 : (z == 2 ? W2 : W3));
  unsigned short* dst = Wt + (size_t)z * D_DIM * D_DIM;
  const int tx = threadIdx.x, ty = threadIdx.y;   // 32 x 8
  const int n0 = blockIdx.x * 32, k0 = blockIdx.y * 32;
  #pragma unroll
  for (int i = 0; i < 4; ++i)
    tile[ty + i * 8][tx] = W[(size_t)(k0 + ty + i * 8) * D_DIM + n0 + tx];
  __syncthreads();
  #pragma unroll
  for (int i = 0; i < 4; ++i)
    dst[(size_t)(n0 + ty + i * 8) * D_DIM + k0 + tx] = f2bf(tile[tx][ty + i * 8]);
}

// ================= 256x256 4-phase bf16 GEMM (merged phases) ================
// C = A[M][K] @ Bt[N][K]^T (+bias). 512 thr = 8 waves (2M x 4N), BK=64,
// LDS 128KB double-buffered, st-swizzled, linear mapping, regular stores.
// R8 change: merge 8 phases -> 4 (one k-step x ALL 32 fragments = 32 MFMA
// between barriers). R6/R7 post-mortems: with 1 block/CU every barrier is
// exposed (~330cy x 16/iter = 5200cy vs 4960cy MFMA); halving barrier count
// attacks the measured tax directly. Total ds_reads/stages/iter unchanged.
// Buffer-hazard proof (write-issue phase > last-read phase, >=1 barrier gap):
//   buf0-A read ph1 / staged ph2; buf0-B read ph2 / staged ph3;
//   buf1-A read ph3 / staged ph4; buf1-B read ph4 / staged next-ph1.
// Readiness: vmcnt(4) at ph2/ph4 end drains exactly the 2 half-tiles the
// following phase reads (newest A-stage stays in flight).
// sched_barrier(0) pins KEPT (R3: removing them races under graph replay).

#define SYNC_MID()                                          \
  do {                                                      \
    __builtin_amdgcn_sched_barrier(0);                      \
    __builtin_amdgcn_s_barrier();                           \
    __builtin_amdgcn_sched_barrier(0);                      \
  } while (0)

#define SYNC_END()                                          \
  do {                                                      \
    __builtin_amdgcn_sched_barrier(0);                      \
    __builtin_amdgcn_s_barrier();                           \
    __builtin_amdgcn_sched_barrier(0);                      \
  } while (0)

// read 4 m-frags x 2 kk of A (half the M extent): 8 x ds_read_b128
#define READ_A(buf, mh, AF)                                               \
  do {                                                                    \
    const char* _ab = (const char*)&lds[buf][0][0];                       \
    _Pragma("unroll") for (int m = 0; m < 4; ++m) {                       \
      _Pragma("unroll") for (int kk = 0; kk < 2; ++kk) {                  \
        AF[m * 2 + kk] = *(const bf16x8*)(_ab +                           \
            (wm * 128 + (mh) * 64 + m * 16 + fr) * 128 +                  \
            (((kk * 4 + lk8) ^ swz) << 4));                               \
      }                                                                   \
    }                                                                     \
  } while (0)

// read all 4 n-frags of B at one kk: 4 x ds_read_b128
#define READ_B4(buf, kk)                                                  \
  do {                                                                    \
    const char* _bb = (const char*)&lds[buf][1][0];                       \
    _Pragma("unroll") for (int n = 0; n < 4; ++n) {                       \
      bf[n] = *(const bf16x8*)(_bb +                                      \
          (wn * 64 + n * 16 + fr) * 128 +                                 \
          ((((kk) * 4 + lk8) ^ swz) << 4));                               \
    }                                                                     \
  } while (0)

// one k-step over all 8x4 fragments: 32 MFMA
#define MFMA_HALF(kk)                                                     \
  do {                                                                    \
    _Pragma("unroll") for (int mm = 0; mm < 8; ++mm) {                    \
      _Pragma("unroll") for (int n = 0; n < 4; ++n) {                     \
        acc[mm][n] = __builtin_amdgcn_mfma_f32_16x16x32_bf16(             \
            af[mm * 2 + (kk)], bf[n], acc[mm][n], 0, 0, 0);               \
      }                                                                   \
    }                                                                     \
  } while (0)

template<bool QKV>
__global__ __launch_bounds__(512, 2) void gemm256_kernel(
    const unsigned short* __restrict__ A,
    const unsigned short* __restrict__ Bt,
    const float* __restrict__ bias0,
    const float* __restrict__ bias1,
    const float* __restrict__ bias2,
    void* __restrict__ outp) {
  constexpr int K = 2048;
  constexpr int NT = 32;                 // K / 64
  __shared__ __align__(16) unsigned short lds[2][2][16384];  // [buf][A/B], 128 KiB

  const int tid = threadIdx.x;
  const int wave = tid >> 6;
  const int lane = tid & 63;
  const int fr = lane & 15;
  const int lk8 = lane >> 4;             // 0..3
  const int wm = wave >> 2;              // 0..1
  const int wn = wave & 3;               // 0..3
  const int swz = fr & 7;                // read-side XOR (16B units)

  // T1: bijective XCD swizzle (nwg % 8 == 0), linear mi/ni (R2-verified)
  const int nwg = gridDim.x;
  const int orig = blockIdx.x;
  const int wg = (orig & 7) * (nwg >> 3) + (orig >> 3);
  const int mi = wg & 63;                // 64 M-blocks
  const int ni = wg >> 6;

  const unsigned short* Ag = A + (size_t)(mi * 256) * K;
  const unsigned short* Bg = Bt + (size_t)(ni * 256) * K;
  const int k8s = (lane & 7) ^ (lane >> 3);   // pre-swizzled source k-octet

  // stage one half-tile (128 rows x 64 k) : 2 x global_load_lds per thread
  auto stageA = [&](int tt, int half) {
    unsigned short* dst = &lds[tt & 1][0][0];
    #pragma unroll
    for (int j = 0; j < 2; ++j) {
      const int c = wave * 128 + j * 64 + lane;
      const int r = half * 128 + (c >> 3);
      gload_lds16(Ag + (size_t)r * K + tt * 64 + k8s * 8,
                  dst + (size_t)(half * 1024 + c) * 8);
    }
  };
  auto stageB = [&](int tt, int half) {
    unsigned short* dst = &lds[tt & 1][1][0];
    #pragma unroll
    for (int j = 0; j < 2; ++j) {
      const int c = wave * 128 + j * 64 + lane;
      const int r = half * 128 + (c >> 3);
      gload_lds16(Bg + (size_t)r * K + tt * 64 + k8s * 8,
                  dst + (size_t)(half * 1024 + c) * 8);
    }
  };

  f32x4 acc[8][4];
  #pragma unroll
  for (int m = 0; m < 8; ++m)
    #pragma unroll
    for (int n = 0; n < 4; ++n)
      acc[m][n] = (f32x4){0.f, 0.f, 0.f, 0.f};

  // prologue: tile0 fully + tile1 A-halves; drain to 4 (A(t1) in flight)
  stageA(0, 0); stageA(0, 1); stageB(0, 0); stageB(0, 1);
  stageA(1, 0); stageA(1, 1);
  asm volatile("s_waitcnt vmcnt(4)" ::: "memory");
  __builtin_amdgcn_sched_barrier(0);
  __builtin_amdgcn_s_barrier();
  __builtin_amdgcn_sched_barrier(0);

  bf16x8 af[16], bf[4];

  #pragma unroll 1
  for (int t = 0; t < NT; t += 2) {
    // ---- ph1: buf0 kk=0 (stage B(t+1) -> buf1-B) ----
    stageB(t + 1, 0); stageB(t + 1, 1);
    READ_A(0, 0, (af + 0)); READ_A(0, 1, (af + 8));
    READ_B4(0, 0);
    SYNC_MID();
    __builtin_amdgcn_s_setprio(1);
    MFMA_HALF(0);
    __builtin_amdgcn_s_setprio(0);
    SYNC_END();
    // ---- ph2: buf0 kk=1 (stage A(t+2) -> buf0-A; buf0-A last read ph1) ----
    if (t + 2 < NT) { stageA(t + 2, 0); stageA(t + 2, 1); }
    READ_B4(0, 1);
    SYNC_MID();
    __builtin_amdgcn_s_setprio(1);
    MFMA_HALF(1);
    __builtin_amdgcn_s_setprio(0);
    if (t + 2 < NT) { asm volatile("s_waitcnt vmcnt(4)" ::: "memory"); }
    else            { asm volatile("s_waitcnt vmcnt(0)" ::: "memory"); }
    SYNC_END();
    // ---- ph3: buf1 kk=0 (stage B(t+2) -> buf0-B; buf0-B last read ph2) ----
    if (t + 2 < NT) { stageB(t + 2, 0); stageB(t + 2, 1); }
    READ_A(1, 0, (af + 0)); READ_A(1, 1, (af + 8));
    READ_B4(1, 0);
    SYNC_MID();
    __builtin_amdgcn_s_setprio(1);
    MFMA_HALF(0);
    __builtin_amdgcn_s_setprio(0);
    SYNC_END();
    // ---- ph4: buf1 kk=1 (stage A(t+3) -> buf1-A; buf1-A last read ph3) ----
    if (t + 3 < NT) { stageA(t + 3, 0); stageA(t + 3, 1); }
    READ_B4(1, 1);
    SYNC_MID();
    __builtin_amdgcn_s_setprio(1);
    MFMA_HALF(1);
    __builtin_amdgcn_s_setprio(0);
    if (t + 2 < NT) { asm volatile("s_waitcnt vmcnt(4)" ::: "memory"); }
    SYNC_END();
  }

  // epilogue: C/D layout col=lane&15, row=(lane>>4)*4+e (regular stores —
  // NT stores measured -53us in R5: 2B NT stores defeat L2 write-coalescing)
  const int rb = mi * 256 + wm * 128 + (lane >> 4) * 4;
  const int cb = ni * 256 + wn * 64 + fr;
  if constexpr (QKV) {
    const int plane = (ni * 256) >> 11;           // q/k/v plane, blocks never straddle
    const float* bias = plane == 0 ? bias0 : (plane == 1 ? bias1 : bias2);
    unsigned short* out = (unsigned short*)outp + (size_t)plane * M_DIM * D_DIM;
    #pragma unroll
    for (int n4 = 0; n4 < 4; ++n4) {
      const int col = (cb + n4 * 16) & (D_DIM - 1);
      const float bv = bias[col];
      #pragma unroll
      for (int m8 = 0; m8 < 8; ++m8)
        #pragma unroll
        for (int e = 0; e < 4; ++e)
          out[(size_t)(rb + m8 * 16 + e) * D_DIM + col] = f2bf(acc[m8][n4][e] + bv);
    }
  } else {
    float* out = (float*)outp;
    #pragma unroll
    for (int n4 = 0; n4 < 4; ++n4) {
      const int col = cb + n4 * 16;
      const float bv = bias0[col];
      #pragma unroll
      for (int m8 = 0; m8 < 8; ++m8)
        #pragma unroll
        for (int e = 0; e < 4; ++e)
          out[(size_t)(rb + m8 * 16 + e) * D_DIM + col] = acc[m8][n4][e] + bv;
    }
  }
}

// ---------------- per-token head attention ----------------
__global__ __launch_bounds__(256) void attn_kernel(const unsigned short* __restrict__ qkv,
                                                   unsigned short* __restrict__ attnb) {
  __shared__ __align__(16) unsigned short kv_s[4][2][HEADS * HDIM];  // 32 KB
  const int tid = threadIdx.x;
  const int wave = tid >> 6;
  const int lane = tid & 63;
  const int t = blockIdx.x * 4 + wave;
  const size_t MD = (size_t)M_DIM * D_DIM;

  const bf16x8* kg = (const bf16x8*)(qkv + MD + (size_t)t * D_DIM);
  const bf16x8* vg = (const bf16x8*)(qkv + 2 * MD + (size_t)t * D_DIM);
  bf16x8* ks = (bf16x8*)&kv_s[wave][0][0];
  bf16x8* vs = (bf16x8*)&kv_s[wave][1][0];
  #pragma unroll
  for (int i = 0; i < 4; ++i) {
    ks[i * 64 + lane] = kg[i * 64 + lane];
    vs[i * 64 + lane] = vg[i * 64 + lane];
  }

  const int ih = lane >> 2;
  const int qd = lane & 3;
  const int hsrc = (ih & 3) * 4 + (ih >> 2);   // GQA head permutation
  const unsigned short* qg = qkv + (size_t)t * D_DIM + hsrc * HDIM + qd * 32;
  float qreg[32];
  #pragma unroll
  for (int c = 0; c < 4; ++c) {
    bf16x8 q8 = ((const bf16x8*)qg)[c];
    #pragma unroll
    for (int e = 0; e < 8; ++e) qreg[c * 8 + e] = bf2f((unsigned short)q8[e]);
  }

  __syncthreads();

  float s[16];
  #pragma unroll
  for (int j = 0; j < 16; ++j) {
    float acc = 0.f;
    const bf16x8* kp = (const bf16x8*)&kv_s[wave][0][j * HDIM + qd * 32];
    #pragma unroll
    for (int c = 0; c < 4; ++c) {
      bf16x8 k8 = kp[c];
      #pragma unroll
      for (int e = 0; e < 8; ++e) acc = fmaf(qreg[c * 8 + e], bf2f((unsigned short)k8[e]), acc);
    }
    acc += __shfl_xor(acc, 1);
    acc += __shfl_xor(acc, 2);
    s[j] = acc * 0.08838834764831845f;  // 1/sqrt(128)
  }

  float mx = s[0];
  #pragma unroll
  for (int j = 1; j < 16; ++j) mx = fmaxf(mx, s[j]);
  float sum = 0.f;
  #pragma unroll
  for (int j = 0; j < 16; ++j) { s[j] = __expf(s[j] - mx); sum += s[j]; }
  const float inv = 1.f / sum;

  float o[32];
  #pragma unroll
  for (int c = 0; c < 32; ++c) o[c] = 0.f;
  #pragma unroll
  for (int j = 0; j < 16; ++j) {
    const float p = s[j] * inv;
    const bf16x8* vp = (const bf16x8*)&kv_s[wave][1][j * HDIM + qd * 32];
    #pragma unroll
    for (int c = 0; c < 4; ++c) {
      bf16x8 v8 = vp[c];
      #pragma unroll
      for (int e = 0; e < 8; ++e) o[c * 8 + e] = fmaf(p, bf2f((unsigned short)v8[e]), o[c * 8 + e]);
    }
  }

  unsigned short* op = attnb + (size_t)t * D_DIM + ih * HDIM + qd * 32;
  #pragma unroll
  for (int c = 0; c < 4; ++c) {
    bf16x8 ov;
    #pragma unroll
    for (int e = 0; e < 8; ++e) ov[e] = (short)f2bf(o[c * 8 + e]);
    ((bf16x8*)op)[c] = ov;
  }
}

extern "C" void kernel_launch(void* const* d_in, const int* in_sizes, int n_in,
                              void* d_out, int out_size, void* d_ws, size_t ws_size,
                              hipStream_t stream) {
  const float* x  = (const float*)d_in[0];
  const float* Wq = (const float*)d_in[1];
  const float* bq = (const float*)d_in[2];
  const float* Wk = (const float*)d_in[3];
  const float* bk = (const float*)d_in[4];
  const float* Wv = (const float*)d_in[5];
  const float* bv = (const float*)d_in[6];
  const float* Wo = (const float*)d_in[7];
  const float* bo = (const float*)d_in[8];

  const size_t MD = (size_t)M_DIM * D_DIM;   // 33,554,432 elems
  const size_t DD = (size_t)D_DIM * D_DIM;   //  4,194,304 elems

  unsigned short* xb   = (unsigned short*)d_ws;
  unsigned short* Wt   = xb + MD;
  unsigned short* qkvb = Wt + 4 * DD;
  const size_t need_bytes = (MD + 4 * DD + 3 * MD) * sizeof(unsigned short);
  if (ws_size < need_bytes) return;

  // 1) x -> bf16
  cvt_x_kernel<<<2048, 256, 0, stream>>>((const float4*)x, xb, (int)(MD / 4));

  // 2) weights -> bf16 transposed [N][K] (one grid, z = which weight)
  cvt_wt_kernel<<<dim3(64, 64, 4), dim3(32, 8), 0, stream>>>(Wq, Wk, Wv, Wo, Wt);

  // 3) fused QKV GEMM: [16384,2048] @ [2048,6144]^T -> q|k|v bf16 planes
  gemm256_kernel<true><<<64 * 24, 512, 0, stream>>>(xb, Wt, bq, bk, bv, qkvb);

  // 4) per-token head attention -> attn bf16 (reuses xb)
  attn_kernel<<<4096, 256, 0, stream>>>(qkvb, xb);

  // 5) output GEMM: attn @ Wo + bo -> fp32
  gemm256_kernel<false><<<64 * 8, 512, 0, stream>>>(xb, Wt + 3 * DD, bo, nullptr, nullptr, d_out);
}

// Round 9
// 661.732 us; speedup vs baseline: 1.9339x; 1.9339x over previous
//
#include <hip/hip_runtime.h>
#include <stdint.h>

// Problem constants (B=4, S=4096, D=2048, H=16, G=4, hd=128)
#define M_DIM 16384   // B*S tokens
#define D_DIM 2048
#define HEADS 16
#define HDIM 128

typedef __attribute__((ext_vector_type(8))) short bf16x8;
typedef __attribute__((ext_vector_type(16))) float f32x16;

__device__ __forceinline__ unsigned short f2bf(float f) {
  union { float f; uint32_t u; } c; c.f = f;
  uint32_t u = c.u;
  u += 0x7FFFu + ((u >> 16) & 1u);   // round-to-nearest-even
  return (unsigned short)(u >> 16);
}
__device__ __forceinline__ float bf2f(unsigned short h) {
  union { float f; uint32_t u; } c; c.u = ((uint32_t)h) << 16;
  return c.f;
}

__device__ __forceinline__ void gload_lds16(const unsigned short* g, unsigned short* l) {
  __builtin_amdgcn_global_load_lds(
      (const __attribute__((address_space(1))) void*)g,
      (__attribute__((address_space(3))) void*)l,
      16, 0, 0);
}

// ---------------- x (fp32) -> bf16 ----------------
__global__ __launch_bounds__(256) void cvt_x_kernel(const float4* __restrict__ in,
                                                    unsigned short* __restrict__ out,
                                                    int n4) {
  int i = blockIdx.x * blockDim.x + threadIdx.x;
  int stride = gridDim.x * blockDim.x;
  for (; i < n4; i += stride) {
    float4 v = in[i];
    ushort4 o;
    o.x = f2bf(v.x); o.y = f2bf(v.y); o.z = f2bf(v.z); o.w = f2bf(v.w);
    ((ushort4*)out)[i] = o;
  }
}

// ------- W (fp32, [K][N]) -> W^T (bf16, [N][K]), all 4 weights in one grid ----
__global__ __launch_bounds__(256) void cvt_wt_kernel(const float* __restrict__ W0,
                                                     const float* __restrict__ W1,
                                                     const float* __restrict__ W2,
                                                     const float* __restrict__ W3,
                                                     unsigned short* __restrict__ Wt) {
  __shared__ float tile[32][33];
  const int z = blockIdx.z;
  const float* W = z == 0 ? W0 : (z == 1 ? W1 : (z == 2 ? W2 : W3));
  unsigned short* dst = Wt + (size_t)z * D_DIM * D_DIM;
  const int tx = threadIdx.x, ty = threadIdx.y;   // 32 x 8
  const int n0 = blockIdx.x * 32, k0 = blockIdx.y * 32;
  #pragma unroll
  for (int i = 0; i < 4; ++i)
    tile[ty + i * 8][tx] = W[(size_t)(k0 + ty + i * 8) * D_DIM + n0 + tx];
  __syncthreads();
  #pragma unroll
  for (int i = 0; i < 4; ++i)
    dst[(size_t)(n0 + ty + i * 8) * D_DIM + k0 + tx] = f2bf(tile[tx][ty + i * 8]);
}

// ============ 256x256 8-phase bf16 GEMM — R7 skeleton, 32x32x16 MFMA ========
// C = A[M][K] @ Bt[N][K]^T (+bias). 512 thr = 8 waves (2M x 4N), BK=64,
// LDS 128KB double-buffered, st-swizzled, linear mapping, regular stores.
// R9: ONLY the MFMA shape changes (16x16x32 -> 32x32x16; m119: +15% pipe
// ceiling, half the instruction count). Phases/stages/vmcnt/pins and per-
// phase read counts (A:8, B:4 ds_read_b128) are byte-identical to R7 (the
// proven 640us config); R8's phase-merge regression is reverted.
// Frag layout (verified m74/m101): A/B lane l holds row/col=l&31,
// k-octet=(l>>5); C/D col=lane&31, row=(reg&3)+8*(reg>>2)+4*(lane>>5).

#define SYNC_MID()                                          \
  do {                                                      \
    __builtin_amdgcn_sched_barrier(0);                      \
    __builtin_amdgcn_s_barrier();                           \
    __builtin_amdgcn_sched_barrier(0);                      \
  } while (0)

#define SYNC_END()                                          \
  do {                                                      \
    __builtin_amdgcn_sched_barrier(0);                      \
    __builtin_amdgcn_s_barrier();                           \
    __builtin_amdgcn_sched_barrier(0);                      \
  } while (0)

// A frags for one mh half: m in {mh*2, mh*2+1}, kk=0..3 -> 8 x ds_read_b128
// LDS row = wm*128 + (mh*2+m)*32 + (lane&31); k-octet o = kk*2+(lane>>5);
// slot = o ^ (row&7) = o ^ (lane&7)  (store-side pre-swizzle inverse).
#define READ_A32(buf, mh, AF)                                             \
  do {                                                                    \
    const char* _ab = (const char*)&lds[buf][0][0];                       \
    _Pragma("unroll") for (int m = 0; m < 2; ++m) {                       \
      _Pragma("unroll") for (int kk = 0; kk < 4; ++kk) {                  \
        AF[m * 4 + kk] = *(const bf16x8*)(_ab +                           \
            (wm * 128 + ((mh) * 2 + m) * 32 + l31) * 128 +                \
            (((kk * 2 + l5) ^ swz) << 4));                                \
      }                                                                   \
    }                                                                     \
  } while (0)

// B frags for one n-frag: kk=0..3 -> 4 x ds_read_b128
#define READ_B32(buf, nh, BF)                                             \
  do {                                                                    \
    const char* _bb = (const char*)&lds[buf][1][0];                       \
    _Pragma("unroll") for (int kk = 0; kk < 4; ++kk) {                    \
      BF[kk] = *(const bf16x8*)(_bb +                                     \
          (wn * 64 + (nh) * 32 + l31) * 128 +                             \
          (((kk * 2 + l5) ^ swz) << 4));                                  \
    }                                                                     \
  } while (0)

// one quadrant: 2 m-frags x 1 n-frag x 4 kk = 8 MFMA (2 indep chains of 4)
#define MFMA_Q32(mh, nh, AF, BF)                                          \
  do {                                                                    \
    _Pragma("unroll") for (int kk = 0; kk < 4; ++kk) {                    \
      _Pragma("unroll") for (int m = 0; m < 2; ++m) {                     \
        acc[(mh) * 2 + m][nh] = __builtin_amdgcn_mfma_f32_32x32x16_bf16(  \
            AF[m * 4 + kk], BF[kk], acc[(mh) * 2 + m][nh], 0, 0, 0);      \
      }                                                                   \
    }                                                                     \
  } while (0)

template<bool QKV>
__global__ __launch_bounds__(512, 2) void gemm256_kernel(
    const unsigned short* __restrict__ A,
    const unsigned short* __restrict__ Bt,
    const float* __restrict__ bias0,
    const float* __restrict__ bias1,
    const float* __restrict__ bias2,
    void* __restrict__ outp) {
  constexpr int K = 2048;
  constexpr int NT = 32;                 // K / 64
  __shared__ __align__(16) unsigned short lds[2][2][16384];  // [buf][A/B], 128 KiB

  const int tid = threadIdx.x;
  const int wave = tid >> 6;
  const int lane = tid & 63;
  const int l31 = lane & 31;
  const int l5 = lane >> 5;              // 0..1
  const int wm = wave >> 2;              // 0..1
  const int wn = wave & 3;               // 0..3
  const int swz = lane & 7;              // read-side XOR (16B units)

  // T1: bijective XCD swizzle (nwg % 8 == 0), linear mi/ni (R2-verified)
  const int nwg = gridDim.x;
  const int orig = blockIdx.x;
  const int wg = (orig & 7) * (nwg >> 3) + (orig >> 3);
  const int mi = wg & 63;                // 64 M-blocks
  const int ni = wg >> 6;

  const unsigned short* Ag = A + (size_t)(mi * 256) * K;
  const unsigned short* Bg = Bt + (size_t)(ni * 256) * K;
  const int k8s = (lane & 7) ^ (lane >> 3);   // pre-swizzled source k-octet

  // stage one half-tile (128 rows x 64 k) : 2 x global_load_lds per thread
  auto stageA = [&](int tt, int half) {
    unsigned short* dst = &lds[tt & 1][0][0];
    #pragma unroll
    for (int j = 0; j < 2; ++j) {
      const int c = wave * 128 + j * 64 + lane;
      const int r = half * 128 + (c >> 3);
      gload_lds16(Ag + (size_t)r * K + tt * 64 + k8s * 8,
                  dst + (size_t)(half * 1024 + c) * 8);
    }
  };
  auto stageB = [&](int tt, int half) {
    unsigned short* dst = &lds[tt & 1][1][0];
    #pragma unroll
    for (int j = 0; j < 2; ++j) {
      const int c = wave * 128 + j * 64 + lane;
      const int r = half * 128 + (c >> 3);
      gload_lds16(Bg + (size_t)r * K + tt * 64 + k8s * 8,
                  dst + (size_t)(half * 1024 + c) * 8);
    }
  };

  f32x16 acc[4][2];
  #pragma unroll
  for (int m = 0; m < 4; ++m)
    #pragma unroll
    for (int n = 0; n < 2; ++n)
      acc[m][n] = (f32x16)(0.f);

  // prologue: tile0 fully + tile1 A-halves; drain to 4 (A(t1) in flight)
  stageA(0, 0); stageA(0, 1); stageB(0, 0); stageB(0, 1);
  stageA(1, 0); stageA(1, 1);
  asm volatile("s_waitcnt vmcnt(4)" ::: "memory");
  __builtin_amdgcn_sched_barrier(0);
  __builtin_amdgcn_s_barrier();
  __builtin_amdgcn_sched_barrier(0);

  bf16x8 af0[8], af1[8], bf[4];
  READ_A32(0, 0, af0);   // exposed once (prologue)

  #pragma unroll 1
  for (int t = 0; t < NT; t += 2) {
    // ---- K-tile t (buf 0); quadrants (0,0)(1,0)(0,1)(1,1) ----
    // ph1
    stageB(t + 1, 0);
    READ_B32(0, 0, bf);
    SYNC_MID();
    __builtin_amdgcn_s_setprio(1);
    MFMA_Q32(0, 0, af0, bf);
    READ_A32(0, 1, af1);                     // hoisted: ph2 operand
    __builtin_amdgcn_s_setprio(0);
    SYNC_END();
    // ph2
    stageB(t + 1, 1);
    SYNC_MID();
    __builtin_amdgcn_s_setprio(1);
    MFMA_Q32(1, 0, af1, bf);
    __builtin_amdgcn_s_setprio(0);
    SYNC_END();
    // ph3
    if (t + 2 < NT) stageA(t + 2, 0);
    READ_B32(0, 1, bf);
    SYNC_MID();
    __builtin_amdgcn_s_setprio(1);
    MFMA_Q32(0, 1, af0, bf);
    __builtin_amdgcn_s_setprio(0);
    if (t + 2 < NT) { asm volatile("s_waitcnt vmcnt(2)" ::: "memory"); }
    else            { asm volatile("s_waitcnt vmcnt(0)" ::: "memory"); }
    SYNC_END();
    // ph4 (buf1 A-half0 now validated for all waves)
    if (t + 2 < NT) stageA(t + 2, 1);
    SYNC_MID();
    __builtin_amdgcn_s_setprio(1);
    MFMA_Q32(1, 1, af1, bf);
    READ_A32(1, 0, af0);                     // hoisted: buf1 half0
    __builtin_amdgcn_s_setprio(0);
    SYNC_END();
    // ---- K-tile t+1 (buf 1) ----
    // ph5
    if (t + 2 < NT) stageB(t + 2, 0);
    READ_B32(1, 0, bf);
    SYNC_MID();
    __builtin_amdgcn_s_setprio(1);
    MFMA_Q32(0, 0, af0, bf);
    READ_A32(1, 1, af1);                     // hoisted: ph6 operand
    __builtin_amdgcn_s_setprio(0);
    SYNC_END();
    // ph6
    if (t + 2 < NT) stageB(t + 2, 1);
    SYNC_MID();
    __builtin_amdgcn_s_setprio(1);
    MFMA_Q32(1, 0, af1, bf);
    __builtin_amdgcn_s_setprio(0);
    SYNC_END();
    // ph7
    if (t + 3 < NT) stageA(t + 3, 0);
    READ_B32(1, 1, bf);
    SYNC_MID();
    __builtin_amdgcn_s_setprio(1);
    MFMA_Q32(0, 1, af0, bf);
    __builtin_amdgcn_s_setprio(0);
    if (t + 2 < NT) { asm volatile("s_waitcnt vmcnt(2)" ::: "memory"); }
    SYNC_END();
    // ph8 (buf0 tile t+2 now validated for all waves)
    if (t + 3 < NT) stageA(t + 3, 1);
    SYNC_MID();
    __builtin_amdgcn_s_setprio(1);
    MFMA_Q32(1, 1, af1, bf);
    if (t + 2 < NT) READ_A32(0, 0, af0);     // hoisted: next-iter ph1 operand
    __builtin_amdgcn_s_setprio(0);
    SYNC_END();
  }

  // epilogue: 32x32 C/D layout col=lane&31, row=(reg&3)+8*(reg>>2)+4*(lane>>5)
  const int rb = mi * 256 + wm * 128 + 4 * l5;
  const int cbase = ni * 256 + wn * 64 + l31;
  if constexpr (QKV) {
    const int plane = (ni * 256) >> 11;           // q/k/v plane, blocks never straddle
    const float* bias = plane == 0 ? bias0 : (plane == 1 ? bias1 : bias2);
    unsigned short* out = (unsigned short*)outp + (size_t)plane * M_DIM * D_DIM;
    #pragma unroll
    for (int n = 0; n < 2; ++n) {
      const int col = (cbase + n * 32) & (D_DIM - 1);
      const float bv = bias[col];
      #pragma unroll
      for (int m = 0; m < 4; ++m)
        #pragma unroll
        for (int reg = 0; reg < 16; ++reg) {
          const int row = rb + m * 32 + (reg & 3) + 8 * (reg >> 2);
          out[(size_t)row * D_DIM + col] = f2bf(acc[m][n][reg] + bv);
        }
    }
  } else {
    float* out = (float*)outp;
    #pragma unroll
    for (int n = 0; n < 2; ++n) {
      const int col = cbase + n * 32;
      const float bv = bias0[col];
      #pragma unroll
      for (int m = 0; m < 4; ++m)
        #pragma unroll
        for (int reg = 0; reg < 16; ++reg) {
          const int row = rb + m * 32 + (reg & 3) + 8 * (reg >> 2);
          out[(size_t)row * D_DIM + col] = acc[m][n][reg] + bv;
        }
    }
  }
}

// ---------------- per-token head attention ----------------
__global__ __launch_bounds__(256) void attn_kernel(const unsigned short* __restrict__ qkv,
                                                   unsigned short* __restrict__ attnb) {
  __shared__ __align__(16) unsigned short kv_s[4][2][HEADS * HDIM];  // 32 KB
  const int tid = threadIdx.x;
  const int wave = tid >> 6;
  const int lane = tid & 63;
  const int t = blockIdx.x * 4 + wave;
  const size_t MD = (size_t)M_DIM * D_DIM;

  const bf16x8* kg = (const bf16x8*)(qkv + MD + (size_t)t * D_DIM);
  const bf16x8* vg = (const bf16x8*)(qkv + 2 * MD + (size_t)t * D_DIM);
  bf16x8* ks = (bf16x8*)&kv_s[wave][0][0];
  bf16x8* vs = (bf16x8*)&kv_s[wave][1][0];
  #pragma unroll
  for (int i = 0; i < 4; ++i) {
    ks[i * 64 + lane] = kg[i * 64 + lane];
    vs[i * 64 + lane] = vg[i * 64 + lane];
  }

  const int ih = lane >> 2;
  const int qd = lane & 3;
  const int hsrc = (ih & 3) * 4 + (ih >> 2);   // GQA head permutation
  const unsigned short* qg = qkv + (size_t)t * D_DIM + hsrc * HDIM + qd * 32;
  float qreg[32];
  #pragma unroll
  for (int c = 0; c < 4; ++c) {
    bf16x8 q8 = ((const bf16x8*)qg)[c];
    #pragma unroll
    for (int e = 0; e < 8; ++e) qreg[c * 8 + e] = bf2f((unsigned short)q8[e]);
  }

  __syncthreads();

  float s[16];
  #pragma unroll
  for (int j = 0; j < 16; ++j) {
    float acc = 0.f;
    const bf16x8* kp = (const bf16x8*)&kv_s[wave][0][j * HDIM + qd * 32];
    #pragma unroll
    for (int c = 0; c < 4; ++c) {
      bf16x8 k8 = kp[c];
      #pragma unroll
      for (int e = 0; e < 8; ++e) acc = fmaf(qreg[c * 8 + e], bf2f((unsigned short)k8[e]), acc);
    }
    acc += __shfl_xor(acc, 1);
    acc += __shfl_xor(acc, 2);
    s[j] = acc * 0.08838834764831845f;  // 1/sqrt(128)
  }

  float mx = s[0];
  #pragma unroll
  for (int j = 1; j < 16; ++j) mx = fmaxf(mx, s[j]);
  float sum = 0.f;
  #pragma unroll
  for (int j = 0; j < 16; ++j) { s[j] = __expf(s[j] - mx); sum += s[j]; }
  const float inv = 1.f / sum;

  float o[32];
  #pragma unroll
  for (int c = 0; c < 32; ++c) o[c] = 0.f;
  #pragma unroll
  for (int j = 0; j < 16; ++j) {
    const float p = s[j] * inv;
    const bf16x8* vp = (const bf16x8*)&kv_s[wave][1][j * HDIM + qd * 32];
    #pragma unroll
    for (int c = 0; c < 4; ++c) {
      bf16x8 v8 = vp[c];
      #pragma unroll
      for (int e = 0; e < 8; ++e) o[c * 8 + e] = fmaf(p, bf2f((unsigned short)v8[e]), o[c * 8 + e]);
    }
  }

  unsigned short* op = attnb + (size_t)t * D_DIM + ih * HDIM + qd * 32;
  #pragma unroll
  for (int c = 0; c < 4; ++c) {
    bf16x8 ov;
    #pragma unroll
    for (int e = 0; e < 8; ++e) ov[e] = (short)f2bf(o[c * 8 + e]);
    ((bf16x8*)op)[c] = ov;
  }
}

extern "C" void kernel_launch(void* const* d_in, const int* in_sizes, int n_in,
                              void* d_out, int out_size, void* d_ws, size_t ws_size,
                              hipStream_t stream) {
  const float* x  = (const float*)d_in[0];
  const float* Wq = (const float*)d_in[1];
  const float* bq = (const float*)d_in[2];
  const float* Wk = (const float*)d_in[3];
  const float* bk = (const float*)d_in[4];
  const float* Wv = (const float*)d_in[5];
  const float* bv = (const float*)d_in[6];
  const float* Wo = (const float*)d_in[7];
  const float* bo = (const float*)d_in[8];

  const size_t MD = (size_t)M_DIM * D_DIM;   // 33,554,432 elems
  const size_t DD = (size_t)D_DIM * D_DIM;   //  4,194,304 elems

  unsigned short* xb   = (unsigned short*)d_ws;
  unsigned short* Wt   = xb + MD;
  unsigned short* qkvb = Wt + 4 * DD;
  const size_t need_bytes = (MD + 4 * DD + 3 * MD) * sizeof(unsigned short);
  if (ws_size < need_bytes) return;

  // 1) x -> bf16
  cvt_x_kernel<<<2048, 256, 0, stream>>>((const float4*)x, xb, (int)(MD / 4));

  // 2) weights -> bf16 transposed [N][K] (one grid, z = which weight)
  cvt_wt_kernel<<<dim3(64, 64, 4), dim3(32, 8), 0, stream>>>(Wq, Wk, Wv, Wo, Wt);

  // 3) fused QKV GEMM: [16384,2048] @ [2048,6144]^T -> q|k|v bf16 planes
  gemm256_kernel<true><<<64 * 24, 512, 0, stream>>>(xb, Wt, bq, bk, bv, qkvb);

  // 4) per-token head attention -> attn bf16 (reuses xb)
  attn_kernel<<<4096, 256, 0, stream>>>(qkvb, xb);

  // 5) output GEMM: attn @ Wo + bo -> fp32
  gemm256_kernel<false><<<64 * 8, 512, 0, stream>>>(xb, Wt + 3 * DD, bo, nullptr, nullptr, d_out);
}

// Round 10
// 620.560 us; speedup vs baseline: 2.0622x; 1.0663x over previous
//
#include <hip/hip_runtime.h>
#include <stdint.h>

// Problem constants (B=4, S=4096, D=2048, H=16, G=4, hd=128)
#define M_DIM 16384   // B*S tokens
#define D_DIM 2048
#define HEADS 16
#define HDIM 128

typedef __attribute__((ext_vector_type(8))) short bf16x8;
typedef __attribute__((ext_vector_type(4))) float f32x4;

__device__ __forceinline__ unsigned short f2bf(float f) {
  union { float f; uint32_t u; } c; c.f = f;
  uint32_t u = c.u;
  u += 0x7FFFu + ((u >> 16) & 1u);   // round-to-nearest-even
  return (unsigned short)(u >> 16);
}
__device__ __forceinline__ float bf2f(unsigned short h) {
  union { float f; uint32_t u; } c; c.u = ((uint32_t)h) << 16;
  return c.f;
}

__device__ __forceinline__ void gload_lds16(const unsigned short* g, unsigned short* l) {
  __builtin_amdgcn_global_load_lds(
      (const __attribute__((address_space(1))) void*)g,
      (__attribute__((address_space(3))) void*)l,
      16, 0, 0);
}

// ---------------- x (fp32) -> bf16 ----------------
__global__ __launch_bounds__(256) void cvt_x_kernel(const float4* __restrict__ in,
                                                    unsigned short* __restrict__ out,
                                                    int n4) {
  int i = blockIdx.x * blockDim.x + threadIdx.x;
  int stride = gridDim.x * blockDim.x;
  for (; i < n4; i += stride) {
    float4 v = in[i];
    ushort4 o;
    o.x = f2bf(v.x); o.y = f2bf(v.y); o.z = f2bf(v.z); o.w = f2bf(v.w);
    ((ushort4*)out)[i] = o;
  }
}

// ------- W (fp32, [K][N]) -> W^T (bf16, [N][K]), all 4 weights in one grid ----
__global__ __launch_bounds__(256) void cvt_wt_kernel(const float* __restrict__ W0,
                                                     const float* __restrict__ W1,
                                                     const float* __restrict__ W2,
                                                     const float* __restrict__ W3,
                                                     unsigned short* __restrict__ Wt) {
  __shared__ float tile[32][33];
  const int z = blockIdx.z;
  const float* W = z == 0 ? W0 : (z == 1 ? W1 : (z == 2 ? W2 : W3));
  unsigned short* dst = Wt + (size_t)z * D_DIM * D_DIM;
  const int tx = threadIdx.x, ty = threadIdx.y;   // 32 x 8
  const int n0 = blockIdx.x * 32, k0 = blockIdx.y * 32;
  #pragma unroll
  for (int i = 0; i < 4; ++i)
    tile[ty + i * 8][tx] = W[(size_t)(k0 + ty + i * 8) * D_DIM + n0 + tx];
  __syncthreads();
  #pragma unroll
  for (int i = 0; i < 4; ++i)
    dst[(size_t)(n0 + ty + i * 8) * D_DIM + k0 + tx] = f2bf(tile[tx][ty + i * 8]);
}

// ======= 256x256 8-phase bf16 GEMM — R7 skeleton, ni-major block mapping =====
// C = A[M][K] @ Bt[N][K]^T (+bias). 512 thr = 8 waves (2M x 4N), BK=64,
// LDS 128KB double-buffered, st-swizzled, regular stores, 16x16x32 MFMA
// (R9's 32x32 swap reverted: -5..-20us + conflicts).
// R10 change (single variable vs R7): block mapping mi-major -> NI-MAJOR
// (mi = wg/NIB, ni = wg%NIB). Rationale from counters: FETCH=811MB vs 92MB
// working set — the 67MB A-panel is re-fetched from HBM every ni-round
// (L3 doesn't retain it under the write stream) = ~290us of the 407us wall.
// ni-major cohort shares a 1-2MB A slice (L2-resident, mirrors R2's proven
// B-sharing) and streams B — whose 25MB total stays L3-resident after round
// one. Unlike R4's supertile (12MB cohort set, nothing L2-resident), one
// operand stays L2-pinned. Everything else byte-identical to R7.

#define SYNC_MID()                                          \
  do {                                                      \
    __builtin_amdgcn_sched_barrier(0);                      \
    __builtin_amdgcn_s_barrier();                           \
    __builtin_amdgcn_sched_barrier(0);                      \
  } while (0)

#define SYNC_END()                                          \
  do {                                                      \
    __builtin_amdgcn_sched_barrier(0);                      \
    __builtin_amdgcn_s_barrier();                           \
    __builtin_amdgcn_sched_barrier(0);                      \
  } while (0)

#define READ_A(buf, mh, AF)                                               \
  do {                                                                    \
    const char* _ab = (const char*)&lds[buf][0][0];                       \
    _Pragma("unroll") for (int m = 0; m < 4; ++m) {                       \
      _Pragma("unroll") for (int kk = 0; kk < 2; ++kk) {                  \
        AF[m * 2 + kk] = *(const bf16x8*)(_ab +                           \
            (wm * 128 + (mh) * 64 + m * 16 + fr) * 128 +                  \
            (((kk * 4 + lk8) ^ swz) << 4));                               \
      }                                                                   \
    }                                                                     \
  } while (0)

#define READ_B(buf, nh, BF)                                               \
  do {                                                                    \
    const char* _bb = (const char*)&lds[buf][1][0];                       \
    _Pragma("unroll") for (int n = 0; n < 2; ++n) {                       \
      _Pragma("unroll") for (int kk = 0; kk < 2; ++kk) {                  \
        BF[n * 2 + kk] = *(const bf16x8*)(_bb +                           \
            (wn * 64 + (nh) * 32 + n * 16 + fr) * 128 +                   \
            (((kk * 4 + lk8) ^ swz) << 4));                               \
      }                                                                   \
    }                                                                     \
  } while (0)

#define MFMA_Q(mh, nh, AF, BF)                                            \
  do {                                                                    \
    _Pragma("unroll") for (int m = 0; m < 4; ++m) {                       \
      _Pragma("unroll") for (int n = 0; n < 2; ++n) {                     \
        _Pragma("unroll") for (int kk = 0; kk < 2; ++kk) {                \
          acc[(mh) * 4 + m][(nh) * 2 + n] =                               \
              __builtin_amdgcn_mfma_f32_16x16x32_bf16(                    \
                  AF[m * 2 + kk], BF[n * 2 + kk],                         \
                  acc[(mh) * 4 + m][(nh) * 2 + n], 0, 0, 0);              \
        }                                                                 \
      }                                                                   \
    }                                                                     \
  } while (0)

template<bool QKV>
__global__ __launch_bounds__(512, 2) void gemm256_kernel(
    const unsigned short* __restrict__ A,
    const unsigned short* __restrict__ Bt,
    const float* __restrict__ bias0,
    const float* __restrict__ bias1,
    const float* __restrict__ bias2,
    void* __restrict__ outp) {
  constexpr int K = 2048;
  constexpr int NT = 32;                 // K / 64
  constexpr int NIB = QKV ? 24 : 8;      // N-blocks (6144/256 or 2048/256)
  __shared__ __align__(16) unsigned short lds[2][2][16384];  // [buf][A/B], 128 KiB

  const int tid = threadIdx.x;
  const int wave = tid >> 6;
  const int lane = tid & 63;
  const int fr = lane & 15;
  const int lk8 = lane >> 4;             // 0..3
  const int wm = wave >> 2;              // 0..1
  const int wn = wave & 3;               // 0..3
  const int swz = fr & 7;                // read-side XOR (16B units)

  // T1: bijective XCD swizzle (nwg % 8 == 0) + NI-MAJOR linear mapping
  const int nwg = gridDim.x;
  const int orig = blockIdx.x;
  const int wg = (orig & 7) * (nwg >> 3) + (orig >> 3);
  const int mi = wg / NIB;               // cohort of 32 consecutive wg shares mi
  const int ni = wg - mi * NIB;

  const unsigned short* Ag = A + (size_t)(mi * 256) * K;
  const unsigned short* Bg = Bt + (size_t)(ni * 256) * K;
  const int k8s = (lane & 7) ^ (lane >> 3);   // pre-swizzled source k-octet

  // stage one half-tile (128 rows x 64 k) : 2 x global_load_lds per thread
  auto stageA = [&](int tt, int half) {
    unsigned short* dst = &lds[tt & 1][0][0];
    #pragma unroll
    for (int j = 0; j < 2; ++j) {
      const int c = wave * 128 + j * 64 + lane;
      const int r = half * 128 + (c >> 3);
      gload_lds16(Ag + (size_t)r * K + tt * 64 + k8s * 8,
                  dst + (size_t)(half * 1024 + c) * 8);
    }
  };
  auto stageB = [&](int tt, int half) {
    unsigned short* dst = &lds[tt & 1][1][0];
    #pragma unroll
    for (int j = 0; j < 2; ++j) {
      const int c = wave * 128 + j * 64 + lane;
      const int r = half * 128 + (c >> 3);
      gload_lds16(Bg + (size_t)r * K + tt * 64 + k8s * 8,
                  dst + (size_t)(half * 1024 + c) * 8);
    }
  };

  f32x4 acc[8][4];
  #pragma unroll
  for (int m = 0; m < 8; ++m)
    #pragma unroll
    for (int n = 0; n < 4; ++n)
      acc[m][n] = (f32x4){0.f, 0.f, 0.f, 0.f};

  // prologue: tile0 fully + tile1 A-halves; drain to 4 (A(t1) in flight)
  stageA(0, 0); stageA(0, 1); stageB(0, 0); stageB(0, 1);
  stageA(1, 0); stageA(1, 1);
  asm volatile("s_waitcnt vmcnt(4)" ::: "memory");
  __builtin_amdgcn_sched_barrier(0);
  __builtin_amdgcn_s_barrier();
  __builtin_amdgcn_sched_barrier(0);

  bf16x8 af0[8], af1[8], bf[4];
  READ_A(0, 0, af0);   // exposed once (prologue)

  #pragma unroll 1
  for (int t = 0; t < NT; t += 2) {
    // ---- K-tile t (buf 0); quadrants (0,0)(1,0)(0,1)(1,1) ----
    // ph1
    stageB(t + 1, 0);
    READ_B(0, 0, bf);
    SYNC_MID();
    __builtin_amdgcn_s_setprio(1);
    MFMA_Q(0, 0, af0, bf);
    READ_A(0, 1, af1);                       // hoisted: ph2 operand
    __builtin_amdgcn_s_setprio(0);
    SYNC_END();
    // ph2
    stageB(t + 1, 1);
    SYNC_MID();
    __builtin_amdgcn_s_setprio(1);
    MFMA_Q(1, 0, af1, bf);
    __builtin_amdgcn_s_setprio(0);
    SYNC_END();
    // ph3
    if (t + 2 < NT) stageA(t + 2, 0);
    READ_B(0, 1, bf);
    SYNC_MID();
    __builtin_amdgcn_s_setprio(1);
    MFMA_Q(0, 1, af0, bf);
    __builtin_amdgcn_s_setprio(0);
    if (t + 2 < NT) { asm volatile("s_waitcnt vmcnt(2)" ::: "memory"); }
    else            { asm volatile("s_waitcnt vmcnt(0)" ::: "memory"); }
    SYNC_END();
    // ph4 (buf1 A-half0 now validated for all waves)
    if (t + 2 < NT) stageA(t + 2, 1);
    SYNC_MID();
    __builtin_amdgcn_s_setprio(1);
    MFMA_Q(1, 1, af1, bf);
    READ_A(1, 0, af0);                       // hoisted: buf1 half0
    __builtin_amdgcn_s_setprio(0);
    SYNC_END();
    // ---- K-tile t+1 (buf 1) ----
    // ph5
    if (t + 2 < NT) stageB(t + 2, 0);
    READ_B(1, 0, bf);
    SYNC_MID();
    __builtin_amdgcn_s_setprio(1);
    MFMA_Q(0, 0, af0, bf);
    READ_A(1, 1, af1);                       // hoisted: ph6 operand
    __builtin_amdgcn_s_setprio(0);
    SYNC_END();
    // ph6
    if (t + 2 < NT) stageB(t + 2, 1);
    SYNC_MID();
    __builtin_amdgcn_s_setprio(1);
    MFMA_Q(1, 0, af1, bf);
    __builtin_amdgcn_s_setprio(0);
    SYNC_END();
    // ph7
    if (t + 3 < NT) stageA(t + 3, 0);
    READ_B(1, 1, bf);
    SYNC_MID();
    __builtin_amdgcn_s_setprio(1);
    MFMA_Q(0, 1, af0, bf);
    __builtin_amdgcn_s_setprio(0);
    if (t + 2 < NT) { asm volatile("s_waitcnt vmcnt(2)" ::: "memory"); }
    SYNC_END();
    // ph8 (buf0 tile t+2 now validated for all waves)
    if (t + 3 < NT) stageA(t + 3, 1);
    SYNC_MID();
    __builtin_amdgcn_s_setprio(1);
    MFMA_Q(1, 1, af1, bf);
    if (t + 2 < NT) READ_A(0, 0, af0);       // hoisted: next-iter ph1 operand
    __builtin_amdgcn_s_setprio(0);
    SYNC_END();
  }

  // epilogue: C/D layout col=lane&15, row=(lane>>4)*4+e (regular stores —
  // NT stores measured -53us in R5: 2B NT stores defeat L2 write-coalescing)
  const int rb = mi * 256 + wm * 128 + (lane >> 4) * 4;
  const int cb = ni * 256 + wn * 64 + fr;
  if constexpr (QKV) {
    const int plane = (ni * 256) >> 11;           // q/k/v plane, blocks never straddle
    const float* bias = plane == 0 ? bias0 : (plane == 1 ? bias1 : bias2);
    unsigned short* out = (unsigned short*)outp + (size_t)plane * M_DIM * D_DIM;
    #pragma unroll
    for (int n4 = 0; n4 < 4; ++n4) {
      const int col = (cb + n4 * 16) & (D_DIM - 1);
      const float bv = bias[col];
      #pragma unroll
      for (int m8 = 0; m8 < 8; ++m8)
        #pragma unroll
        for (int e = 0; e < 4; ++e)
          out[(size_t)(rb + m8 * 16 + e) * D_DIM + col] = f2bf(acc[m8][n4][e] + bv);
    }
  } else {
    float* out = (float*)outp;
    #pragma unroll
    for (int n4 = 0; n4 < 4; ++n4) {
      const int col = cb + n4 * 16;
      const float bv = bias0[col];
      #pragma unroll
      for (int m8 = 0; m8 < 8; ++m8)
        #pragma unroll
        for (int e = 0; e < 4; ++e)
          out[(size_t)(rb + m8 * 16 + e) * D_DIM + col] = acc[m8][n4][e] + bv;
    }
  }
}

// ---------------- per-token head attention ----------------
__global__ __launch_bounds__(256) void attn_kernel(const unsigned short* __restrict__ qkv,
                                                   unsigned short* __restrict__ attnb) {
  __shared__ __align__(16) unsigned short kv_s[4][2][HEADS * HDIM];  // 32 KB
  const int tid = threadIdx.x;
  const int wave = tid >> 6;
  const int lane = tid & 63;
  const int t = blockIdx.x * 4 + wave;
  const size_t MD = (size_t)M_DIM * D_DIM;

  const bf16x8* kg = (const bf16x8*)(qkv + MD + (size_t)t * D_DIM);
  const bf16x8* vg = (const bf16x8*)(qkv + 2 * MD + (size_t)t * D_DIM);
  bf16x8* ks = (bf16x8*)&kv_s[wave][0][0];
  bf16x8* vs = (bf16x8*)&kv_s[wave][1][0];
  #pragma unroll
  for (int i = 0; i < 4; ++i) {
    ks[i * 64 + lane] = kg[i * 64 + lane];
    vs[i * 64 + lane] = vg[i * 64 + lane];
  }

  const int ih = lane >> 2;
  const int qd = lane & 3;
  const int hsrc = (ih & 3) * 4 + (ih >> 2);   // GQA head permutation
  const unsigned short* qg = qkv + (size_t)t * D_DIM + hsrc * HDIM + qd * 32;
  float qreg[32];
  #pragma unroll
  for (int c = 0; c < 4; ++c) {
    bf16x8 q8 = ((const bf16x8*)qg)[c];
    #pragma unroll
    for (int e = 0; e < 8; ++e) qreg[c * 8 + e] = bf2f((unsigned short)q8[e]);
  }

  __syncthreads();

  float s[16];
  #pragma unroll
  for (int j = 0; j < 16; ++j) {
    float acc = 0.f;
    const bf16x8* kp = (const bf16x8*)&kv_s[wave][0][j * HDIM + qd * 32];
    #pragma unroll
    for (int c = 0; c < 4; ++c) {
      bf16x8 k8 = kp[c];
      #pragma unroll
      for (int e = 0; e < 8; ++e) acc = fmaf(qreg[c * 8 + e], bf2f((unsigned short)k8[e]), acc);
    }
    acc += __shfl_xor(acc, 1);
    acc += __shfl_xor(acc, 2);
    s[j] = acc * 0.08838834764831845f;  // 1/sqrt(128)
  }

  float mx = s[0];
  #pragma unroll
  for (int j = 1; j < 16; ++j) mx = fmaxf(mx, s[j]);
  float sum = 0.f;
  #pragma unroll
  for (int j = 0; j < 16; ++j) { s[j] = __expf(s[j] - mx); sum += s[j]; }
  const float inv = 1.f / sum;

  float o[32];
  #pragma unroll
  for (int c = 0; c < 32; ++c) o[c] = 0.f;
  #pragma unroll
  for (int j = 0; j < 16; ++j) {
    const float p = s[j] * inv;
    const bf16x8* vp = (const bf16x8*)&kv_s[wave][1][j * HDIM + qd * 32];
    #pragma unroll
    for (int c = 0; c < 4; ++c) {
      bf16x8 v8 = vp[c];
      #pragma unroll
      for (int e = 0; e < 8; ++e) o[c * 8 + e] = fmaf(p, bf2f((unsigned short)v8[e]), o[c * 8 + e]);
    }
  }

  unsigned short* op = attnb + (size_t)t * D_DIM + ih * HDIM + qd * 32;
  #pragma unroll
  for (int c = 0; c < 4; ++c) {
    bf16x8 ov;
    #pragma unroll
    for (int e = 0; e < 8; ++e) ov[e] = (short)f2bf(o[c * 8 + e]);
    ((bf16x8*)op)[c] = ov;
  }
}

extern "C" void kernel_launch(void* const* d_in, const int* in_sizes, int n_in,
                              void* d_out, int out_size, void* d_ws, size_t ws_size,
                              hipStream_t stream) {
  const float* x  = (const float*)d_in[0];
  const float* Wq = (const float*)d_in[1];
  const float* bq = (const float*)d_in[2];
  const float* Wk = (const float*)d_in[3];
  const float* bk = (const float*)d_in[4];
  const float* Wv = (const float*)d_in[5];
  const float* bv = (const float*)d_in[6];
  const float* Wo = (const float*)d_in[7];
  const float* bo = (const float*)d_in[8];

  const size_t MD = (size_t)M_DIM * D_DIM;   // 33,554,432 elems
  const size_t DD = (size_t)D_DIM * D_DIM;   //  4,194,304 elems

  unsigned short* xb   = (unsigned short*)d_ws;
  unsigned short* Wt   = xb + MD;
  unsigned short* qkvb = Wt + 4 * DD;
  const size_t need_bytes = (MD + 4 * DD + 3 * MD) * sizeof(unsigned short);
  if (ws_size < need_bytes) return;

  // 1) x -> bf16
  cvt_x_kernel<<<2048, 256, 0, stream>>>((const float4*)x, xb, (int)(MD / 4));

  // 2) weights -> bf16 transposed [N][K] (one grid, z = which weight)
  cvt_wt_kernel<<<dim3(64, 64, 4), dim3(32, 8), 0, stream>>>(Wq, Wk, Wv, Wo, Wt);

  // 3) fused QKV GEMM: [16384,2048] @ [2048,6144]^T -> q|k|v bf16 planes
  gemm256_kernel<true><<<64 * 24, 512, 0, stream>>>(xb, Wt, bq, bk, bv, qkvb);

  // 4) per-token head attention -> attn bf16 (reuses xb)
  attn_kernel<<<4096, 256, 0, stream>>>(qkvb, xb);

  // 5) output GEMM: attn @ Wo + bo -> fp32
  gemm256_kernel<false><<<64 * 8, 512, 0, stream>>>(xb, Wt + 3 * DD, bo, nullptr, nullptr, d_out);
}